// Round 18
// baseline (129.921 us; speedup 1.0000x reference)
//
#include <hip/hip_runtime.h>
#include <hip/hip_bf16.h>
#include <stdint.h>

// SelfBallPointQuery: B=16, C=3, N=2048, RADIUS^2=0.04, MAX_SAMPLES=64.
// R18: INSTRUMENTATION ROUND #2 (rep=4 on the exact R17 body, asm retained).
// Purpose: separate fixed ramp from per-pass cost. R16 (pre-asm, rep=2) gave
// ramp + 2p = 44.6us, marginal pass 16.6us. This round measures ramp + 4p
// with the VOP3P-forced math:
//   p ~= 11us -> asm worked; steady-state is issue-bound at the reduced
//               count; bench neutrality was fixed gap/ramp. (kernel ~55us)
//   p ~= 16.6us -> asm neutral; VALU count was not binding. (kernel ~77us)
// Counters (VALUBusy, FETCH, conflicts, occupancy) arbitrate the residual.

#define B_DIM 16
#define N_PTS 2048
#define K_OUT 64
#define R2 0.04f
#define WAVES 8
#define BLOCK_T (WAVES * 64)            // 512
#define JPW (N_PTS / WAVES)             // 256 points per wave
#define WPW (JPW / 32)                  // 8 mask words per lane
#define ROWPAD 65                       // LDS row stride
#define REPS 4                          // instrumentation multiplier

typedef float v2f __attribute__((ext_vector_type(2)));

__global__ __launch_bounds__(BLOCK_T, 4) void ball_query_kernel(
    const float* __restrict__ pcs,   // (B, 3, N)
    int* __restrict__ out)           // (B, N, 64) int32
{
    __shared__ int rows[64 * ROWPAD];
    __shared__ int cntS[WAVES][64];
    __shared__ int qfS[WAVES][64];

    const int b    = blockIdx.x >> 5;
    const int qg   = blockIdx.x & 31;
    const int tid  = threadIdx.x;
    const int wave = __builtin_amdgcn_readfirstlane(tid >> 6); // uniform
    const int lane = tid & 63;

    const float* __restrict__ sx = pcs + (size_t)b * 3 * N_PTS;
    const float* __restrict__ sy = sx + N_PTS;
    const float* __restrict__ sz = sy + N_PTS;

    const int qi = qg * 64 + lane;
    // pre-negated query coords, broadcast into both halves of a VGPR pair
    const float nx = -sx[qi], ny = -sy[qi], nz = -sz[qi];
    const v2f nqx = {nx, nx}, nqy = {ny, ny}, nqz = {nz, nz};

    const int jbase = wave * JPW;
    int* const obase = out + (size_t)(b * N_PTS + qg * 64) * K_OUT;

    for (int rep = 0; rep < REPS; ++rep) {
        // ---- dense test phase: 8 words x 32 bits per lane, VOP3P asm ----
        unsigned mask[WPW];
        for (int t = 0; t < WPW; ++t) {
            unsigned m = 0;
            #pragma unroll
            for (int k = 30; k >= 0; k -= 2) {    // descending pairs
                const int j = jbase + t * 32 + k; // wave-uniform, even
                const v2f px = *(const v2f*)(sx + j);   // s_load path
                const v2f py = *(const v2f*)(sy + j);
                const v2f pz = *(const v2f*)(sz + j);
                v2f dx, dy, dz, xx, yy, zz, s0, d2;
                asm("v_pk_add_f32 %0, %1, %2" : "=v"(dx) : "s"(px), "v"(nqx));
                asm("v_pk_add_f32 %0, %1, %2" : "=v"(dy) : "s"(py), "v"(nqy));
                asm("v_pk_add_f32 %0, %1, %2" : "=v"(dz) : "s"(pz), "v"(nqz));
                asm("v_pk_mul_f32 %0, %1, %1" : "=v"(xx) : "v"(dx));
                asm("v_pk_mul_f32 %0, %1, %1" : "=v"(yy) : "v"(dy));
                asm("v_pk_mul_f32 %0, %1, %1" : "=v"(zz) : "v"(dz));
                asm("v_pk_add_f32 %0, %1, %2" : "=v"(s0) : "v"(xx), "v"(yy));
                asm("v_pk_add_f32 %0, %1, %2" : "=v"(d2) : "v"(s0), "v"(zz));
                m = m + m + (unsigned)(d2.y < R2);
                m = m + m + (unsigned)(d2.x < R2);
            }
            mask[t] = m;
        }

        int cnt = 0;
        #pragma unroll
        for (int t = 0; t < WPW; ++t) cnt += __builtin_popcount(mask[t]);
        int qf = -1;
        #pragma unroll
        for (int t = 0; t < WPW; ++t) {
            if (qf < 0 && mask[t] != 0u)
                qf = jbase + t * 32 + __builtin_ctz(mask[t]);
        }
        cntS[wave][lane] = cnt;
        qfS[wave][lane]  = qf;
        __syncthreads();

        int base = 0, tc = 0, gfirst = 0;
        #pragma unroll
        for (int w = 0; w < WAVES; ++w) {
            const int c = cntS[w][lane];
            const int f = qfS[w][lane];
            if (w < wave) base += c;
            gfirst = (tc == 0 && c > 0) ? f : gfirst;
            tc += c;
        }

        // ---- sparse emit into LDS rows ----
        int slot = base;
        for (int t = 0; t < WPW; ++t) {
            unsigned m = mask[t];
            while (m != 0u && slot < K_OUT) {
                const int k = (int)__builtin_ctz(m);
                rows[lane * ROWPAD + slot] = jbase + t * 32 + k;
                m &= m - 1u;
                ++slot;
            }
        }

        // ---- pad ----
        #pragma unroll
        for (int s0i = 0; s0i < K_OUT / WAVES; ++s0i) {
            const int s = wave * (K_OUT / WAVES) + s0i;
            if (s >= tc) rows[lane * ROWPAD + s] = gfirst;
        }
        __syncthreads();

        // ---- coalesced copy-out ----
        #pragma unroll
        for (int it = 0; it < (64 * K_OUT) / BLOCK_T; ++it) {
            const int idx = it * BLOCK_T + tid;
            const int r = idx >> 6;
            const int c = idx & 63;
            obase[idx] = rows[r * ROWPAD + c];
        }
        __syncthreads();   // rows/cntS reuse safety for next rep
    }
}

extern "C" void kernel_launch(void* const* d_in, const int* in_sizes, int n_in,
                              void* d_out, int out_size, void* d_ws, size_t ws_size,
                              hipStream_t stream) {
    const float* pcs = (const float*)d_in[0];
    int* out = (int*)d_out;
    const int grid = B_DIM * 32;     // 512 blocks
    ball_query_kernel<<<grid, BLOCK_T, 0, stream>>>(pcs, out);
}